// Round 17
// baseline (292.449 us; speedup 1.0000x reference)
//
#include <hip/hip_runtime.h>
#include <hip/hip_fp16.h>

#define B_ 64
#define I_ 1152
#define C_ 32
#define E_ 16
#define D_ 8
#define BC_ 8                // batch rows per block (4 waves, j=2 each)
#define ICt 12               // i's per block
#define NIC (I_/ICt)         // 96 i-chunks
#define ICX (NIC/8)          // 12 i-chunks per XCD slab
#define WROW4 (C_*D_*E_/4)   // 1024 float4 per W[i] (f32)
#define SCE (B_*C_*E_)       // 32768 s-elements
#define WIB 8192             // bytes per W[i] in f16
#define NREP 4               // atomic-accumulator replicas (by ic&3)

// async global->LDS DMA, 16B per lane (dest = wave-uniform base + lane*16)
__device__ __forceinline__ void gload_lds16(const void* g, void* l) {
  typedef __attribute__((address_space(1))) const void GV;
  typedef __attribute__((address_space(3))) void LV;
  __builtin_amdgcn_global_load_lds((GV*)g, (LV*)l, 16, 0, 0);
}

#define WAITVM8() do { asm volatile("s_waitcnt vmcnt(8)" ::: "memory"); \
                       __builtin_amdgcn_sched_barrier(0); } while (0)
#define WAITVM4() do { asm volatile("s_waitcnt vmcnt(4)" ::: "memory"); \
                       __builtin_amdgcn_sched_barrier(0); } while (0)
#define WAITVM0() do { asm volatile("s_waitcnt vmcnt(0)" ::: "memory"); \
                       __builtin_amdgcn_sched_barrier(0); } while (0)
#define WAITLG0() do { asm volatile("s_waitcnt lgkmcnt(0)" ::: "memory"); \
                       __builtin_amdgcn_sched_barrier(0); } while (0)

typedef _Float16 h2v __attribute__((ext_vector_type(2)));

__device__ __forceinline__ float dot2f(__half2 a, __half2 b, float c) {
#if defined(__has_builtin)
#if __has_builtin(__builtin_amdgcn_fdot2)
  return __builtin_amdgcn_fdot2(__builtin_bit_cast(h2v, a),
                                __builtin_bit_cast(h2v, b), c, false);
#else
  float2 fa = __half22float2(a), fb = __half22float2(b);
  return fmaf(fa.x, fb.x, fmaf(fa.y, fb.y, c));
#endif
#else
  float2 fa = __half22float2(a), fb = __half22float2(b);
  return fmaf(fa.x, fb.x, fmaf(fa.y, fb.y, c));
#endif
}

__device__ __forceinline__ float h2bits(float a, float b) {
  return __builtin_bit_cast(float, __float22half2_rn({a, b}));
}

// Inline squash of a raw-summed s-slice: thread holds 8 e's of (b,c); full
// sumsq via one shfl_xor(32) (eh-halves pair up). Returns v[k] = s[k]*scale.
__device__ __forceinline__ void squash8(const float* __restrict__ Srep,
                                        size_t base, float v[8]) {
  float s[8] = {0,0,0,0,0,0,0,0};
#pragma unroll
  for (int r = 0; r < NREP; ++r) {
    const float4* p = (const float4*)(Srep + (size_t)r*SCE + base);
    float4 u = p[0], w = p[1];
    s[0]+=u.x; s[1]+=u.y; s[2]+=u.z; s[3]+=u.w;
    s[4]+=w.x; s[5]+=w.y; s[6]+=w.z; s[7]+=w.w;
  }
  float sq = 0.f;
#pragma unroll
  for (int k = 0; k < 8; ++k) sq = fmaf(s[k], s[k], sq);
  sq += __shfl_xor(sq, 32, 64);                 // combine eh-halves
  float scale = sq / (1.f + sq) / (sqrtf(sq) + 1e-8f);
#pragma unroll
  for (int k = 0; k < 8; ++k) v[k] = s[k] * scale;
}

// ---------------- Pass 0 (f32, uniform coef) + convert + atomic-S0 ---------
// r13-proven structure; partial store replaced by 16 f32 unsafeAtomicAdd
// into replica (ic&3) of S0 (cells distinct within a block -> no intra-block
// contention; 24 adds/cell/replica across blocks).
__global__ __launch_bounds__(256)
void caps_pass0(const float* __restrict__ x, const float* __restrict__ W,
                float* __restrict__ S0, __half* __restrict__ Wh,
                __half2* __restrict__ xh)
{
  __shared__ float4 Wl[3][1024];      // 3 x 16KB f32 W buffers
  __shared__ float4 xl[BC_*ICt*2];    // 192 float4 (3KB) f32 x

  const int t     = threadIdx.x;
  const int c     = t & 31;
  const int eh    = (t >> 5) & 1;
  const int bq    = t >> 6;
  const int xcd   = blockIdx.x & 7;
  const int sl    = blockIdx.x >> 3;  // 0..95
  const int ic    = xcd * ICX + (sl >> 3);
  const int bslab = sl & 7;
  const int b0    = bslab * BC_;
  const int i0    = ic * ICt;

  int fsrc[4];
#pragma unroll
  for (int k = 0; k < 4; ++k) {
    int cc = (t >> 5) + 8*k;
    fsrc[k] = cc*32 + ((c - cc) & 31);
  }

  if (t < BC_*ICt*2) {
    int b = t / (ICt*2), r = t % (ICt*2);
    xl[t] = ((const float4*)x)[ ((size_t)(b0 + b)*I_ + i0)*2 + r ];
  }

  const float4* wg = (const float4*)(W + (size_t)i0 * (C_*D_*E_));
#pragma unroll
  for (int k = 0; k < 4; ++k) gload_lds16(wg + fsrc[k],          &Wl[0][t + 256*k]);
#pragma unroll
  for (int k = 0; k < 4; ++k) gload_lds16(wg + WROW4 + fsrc[k],  &Wl[1][t + 256*k]);

  float acc[2][8];
#pragma unroll
  for (int j = 0; j < 2; ++j)
#pragma unroll
    for (int e = 0; e < 8; ++e) acc[j][e] = 0.f;

  int cur = 0;
  for (int ii = 0; ii < ICt; ++ii) {
    WAITLG0();
    __builtin_amdgcn_s_barrier();
    __builtin_amdgcn_sched_barrier(0);

    if (ii + 2 < ICt) {
      int pre = cur + 2; if (pre >= 3) pre -= 3;
      const float4* wn = wg + (size_t)(ii + 2) * WROW4;
#pragma unroll
      for (int k = 0; k < 4; ++k)
        gload_lds16(wn + fsrc[k], &Wl[pre][t + 256*k]);
    }

    if (ii < ICt - 2)       WAITVM8();
    else if (ii == ICt - 2) WAITVM4();
    else                    WAITVM0();
    __builtin_amdgcn_s_barrier();
    __builtin_amdgcn_sched_barrier(0);

    __builtin_amdgcn_s_setprio(1);
    float xv[2][8];
#pragma unroll
    for (int j = 0; j < 2; ++j) {
      float4 a = xl[(bq*2 + j)*(ICt*2) + ii*2 + 0];
      float4 b = xl[(bq*2 + j)*(ICt*2) + ii*2 + 1];
      xv[j][0]=a.x; xv[j][1]=a.y; xv[j][2]=a.z; xv[j][3]=a.w;
      xv[j][4]=b.x; xv[j][5]=b.y; xv[j][6]=b.z; xv[j][7]=b.w;
    }

    float uh[2][8];
#pragma unroll
    for (int j = 0; j < 2; ++j)
#pragma unroll
      for (int e = 0; e < 8; ++e) uh[j][e] = 0.f;

#pragma unroll
    for (int d = 0; d < D_; ++d) {
#pragma unroll
      for (int qq = 0; qq < 2; ++qq) {
        float4 wv = Wl[cur][c*32 + (((d*4 + eh*2 + qq) + c) & 31)];
        const int eb = qq*4;
#pragma unroll
        for (int j = 0; j < 2; ++j) {
          uh[j][eb+0] = fmaf(xv[j][d], wv.x, uh[j][eb+0]);
          uh[j][eb+1] = fmaf(xv[j][d], wv.y, uh[j][eb+1]);
          uh[j][eb+2] = fmaf(xv[j][d], wv.z, uh[j][eb+2]);
          uh[j][eb+3] = fmaf(xv[j][d], wv.w, uh[j][eb+3]);
        }
      }
    }

#pragma unroll
    for (int j = 0; j < 2; ++j)
#pragma unroll
      for (int e = 0; e < 8; ++e) acc[j][e] = fmaf((1.0f/C_), uh[j][e], acc[j][e]);
    __builtin_amdgcn_s_setprio(0);

    cur = (cur + 1 == 3) ? 0 : cur + 1;
  }

  // atomic accumulate into S0 replica (fire-and-forget; drains at kernel end)
#pragma unroll
  for (int j = 0; j < 2; ++j) {
    float* dst = S0 + (size_t)(ic & 3)*SCE
               + (size_t)(b0 + bq*2 + j)*(C_*E_) + c*E_ + eh*8;
#pragma unroll
    for (int e = 0; e < 8; ++e) unsafeAtomicAdd(dst + e, acc[j][e]);
  }

  // epilogue converts (needed only by the NEXT kernel)
  for (int ii = bslab; ii < ICt; ii += 8) {
    const int i = i0 + ii;
    const float4* src = (const float4*)(W + (size_t)i * (C_*D_*E_));
#pragma unroll
    for (int g = 0; g < 2; ++g) {
      int G  = t*2 + g;
      int cc = G >> 4, q = G & 15;
      int d  = q >> 1, eo = q & 1;
      const float4* s4 = src + (cc*8 + d)*4 + eo*2;
      float4 a = s4[0], b = s4[1];
      float4 o;
      o.x = h2bits(a.x, a.y); o.y = h2bits(a.z, a.w);
      o.z = h2bits(b.x, b.y); o.w = h2bits(b.z, b.w);
      *(float4*)(Wh + (size_t)i * 4096 + G*8) = o;
    }
  }
  if (t < BC_*ICt*2) {
    int b = t / (ICt*2), r = t % (ICt*2);
    float4 a = xl[t];
    float4 o;
    o.x = h2bits(a.x, a.x); o.y = h2bits(a.y, a.y);
    o.z = h2bits(a.z, a.z); o.w = h2bits(a.w, a.w);
    size_t idx = ((size_t)(b0 + b)*I_ + (i0 + (r >> 1)))*D_ + (r & 1)*4;
    *(float4*)(xh + idx) = o;
  }
}

// ---------------- Passes 1,2: packed-f16, inline squash, atomic-Sout -------
// TWO=false: v = squash(Sa) (pass 1).  TWO=true: v = squash(Sa)+squash(Sb)
// (pass 2; vacc never materialized). Main loop = r13's f16 PER=2 pipeline.
template<bool TWO>
__global__ __launch_bounds__(256)
void caps_pass_f16(const __half2* __restrict__ xh, const char* __restrict__ Wh,
                   const float* __restrict__ Sa, const float* __restrict__ Sb,
                   float* __restrict__ Sout)
{
  __shared__ float4 Wl[3][1024];      // 3 x 16KB buffers (2 W-i's each)
  __shared__ __half2 xl[BC_*ICt*D_];  // 768 half2 (3KB)

  const int t   = threadIdx.x;
  const int c   = t & 31;
  const int eh  = (t >> 5) & 1;
  const int bq  = t >> 6;
  const int xcd = blockIdx.x & 7;
  const int sl  = blockIdx.x >> 3;    // 0..95
  const int ic  = xcd * ICX + (sl >> 3);
  const int b0  = (sl & 7) * BC_;
  const int i0  = ic * ICt;

  int fsrc[2];
#pragma unroll
  for (int k = 0; k < 2; ++k) {
    int g = t + 256*k, cc = g >> 4, q = g & 15;
    fsrc[k] = cc*256 + ((q ^ (cc & 15)) << 4);    // byte offset in Wh[i]
  }

  // prologue: inline squash of raw sums -> routing vector in f16 pairs
  __half2 vrp[2][4];
#pragma unroll
  for (int j = 0; j < 2; ++j) {
    size_t base = (size_t)(b0 + bq*2 + j)*(C_*E_) + c*E_ + eh*8;
    float v[8];
    squash8(Sa, base, v);
    if (TWO) {
      float v1[8];
      squash8(Sb, base, v1);
#pragma unroll
      for (int k = 0; k < 8; ++k) v[k] += v1[k];
    }
#pragma unroll
    for (int q = 0; q < 4; ++q)
      vrp[j][q] = __float22half2_rn({v[2*q], v[2*q+1]});
  }

  if (t < BC_*ICt*D_/4) {
    int b = t / 24, r = t % 24;
    float4 v = ((const float4*)(xh + ((size_t)(b0 + b)*I_ + i0)*D_))[r];
    ((float4*)xl)[b*24 + r] = v;
  }

  const char* wg = Wh + (size_t)i0 * WIB;
#pragma unroll
  for (int k = 0; k < 4; ++k)
    gload_lds16(wg + (k>>1)*WIB + fsrc[k&1], (char*)&Wl[0][0] + (t + 256*k)*16);
#pragma unroll
  for (int k = 0; k < 4; ++k)
    gload_lds16(wg + WIB*2 + (k>>1)*WIB + fsrc[k&1], (char*)&Wl[1][0] + (t + 256*k)*16);

  __half2 accp[2][4];
#pragma unroll
  for (int j = 0; j < 2; ++j)
#pragma unroll
    for (int q = 0; q < 4; ++q) accp[j][q] = __half2{__half(0.f), __half(0.f)};

  int cur = 0;
  for (int p = 0; p < ICt/2; ++p) {
    WAITLG0();
    __builtin_amdgcn_s_barrier();
    __builtin_amdgcn_sched_barrier(0);

    if (p + 2 < ICt/2) {
      int pre = cur + 2; if (pre >= 3) pre -= 3;
      const char* wn = wg + (size_t)(p + 2) * (2*WIB);
#pragma unroll
      for (int k = 0; k < 4; ++k)
        gload_lds16(wn + (k>>1)*WIB + fsrc[k&1], (char*)&Wl[pre][0] + (t + 256*k)*16);
    }

    if (p < ICt/2 - 2)       WAITVM8();
    else if (p == ICt/2 - 2) WAITVM4();
    else                     WAITVM0();
    __builtin_amdgcn_s_barrier();
    __builtin_amdgcn_sched_barrier(0);

    __builtin_amdgcn_s_setprio(1);
#pragma unroll
    for (int il = 0; il < 2; ++il) {
      const int ii = p*2 + il;

      __half2 xd0[8], xd1[8];
      {
        const float4* xr = (const float4*)xl;
        float4 a0 = xr[((bq*2 + 0)*ICt + ii)*2 + 0];
        float4 b0v = xr[((bq*2 + 0)*ICt + ii)*2 + 1];
        float4 a1 = xr[((bq*2 + 1)*ICt + ii)*2 + 0];
        float4 b1v = xr[((bq*2 + 1)*ICt + ii)*2 + 1];
        xd0[0]=__builtin_bit_cast(__half2,a0.x); xd0[1]=__builtin_bit_cast(__half2,a0.y);
        xd0[2]=__builtin_bit_cast(__half2,a0.z); xd0[3]=__builtin_bit_cast(__half2,a0.w);
        xd0[4]=__builtin_bit_cast(__half2,b0v.x); xd0[5]=__builtin_bit_cast(__half2,b0v.y);
        xd0[6]=__builtin_bit_cast(__half2,b0v.z); xd0[7]=__builtin_bit_cast(__half2,b0v.w);
        xd1[0]=__builtin_bit_cast(__half2,a1.x); xd1[1]=__builtin_bit_cast(__half2,a1.y);
        xd1[2]=__builtin_bit_cast(__half2,a1.z); xd1[3]=__builtin_bit_cast(__half2,a1.w);
        xd1[4]=__builtin_bit_cast(__half2,b1v.x); xd1[5]=__builtin_bit_cast(__half2,b1v.y);
        xd1[6]=__builtin_bit_cast(__half2,b1v.z); xd1[7]=__builtin_bit_cast(__half2,b1v.w);
      }

      __half2 uhp[2][4];
#pragma unroll
      for (int j = 0; j < 2; ++j)
#pragma unroll
        for (int q = 0; q < 4; ++q) uhp[j][q] = __half2{__half(0.f), __half(0.f)};

      const char* wrow = (const char*)&Wl[cur][0] + il*WIB + c*256;
#pragma unroll
      for (int d = 0; d < D_; ++d) {
        float4 w4 = *(const float4*)(wrow + ((((d*2 + eh) ^ (c & 15))) << 4));
        __half2 w0 = __builtin_bit_cast(__half2, w4.x);
        __half2 w1 = __builtin_bit_cast(__half2, w4.y);
        __half2 w2 = __builtin_bit_cast(__half2, w4.z);
        __half2 w3 = __builtin_bit_cast(__half2, w4.w);
        uhp[0][0] = __hfma2(xd0[d], w0, uhp[0][0]);
        uhp[0][1] = __hfma2(xd0[d], w1, uhp[0][1]);
        uhp[0][2] = __hfma2(xd0[d], w2, uhp[0][2]);
        uhp[0][3] = __hfma2(xd0[d], w3, uhp[0][3]);
        uhp[1][0] = __hfma2(xd1[d], w0, uhp[1][0]);
        uhp[1][1] = __hfma2(xd1[d], w1, uhp[1][1]);
        uhp[1][2] = __hfma2(xd1[d], w2, uhp[1][2]);
        uhp[1][3] = __hfma2(xd1[d], w3, uhp[1][3]);
      }

      float coef[2];
#pragma unroll
      for (int j = 0; j < 2; ++j) {
        float lg = 0.f;
#pragma unroll
        for (int q = 0; q < 4; ++q) lg = dot2f(uhp[j][q], vrp[j][q], lg);
        lg += __shfl_xor(lg, 32, 64);          // combine e-halves
        float pexp = __expf(lg);               // no max-sub: |lg| bounded
        float s = pexp;
#pragma unroll
        for (int mk = 16; mk >= 1; mk >>= 1) s += __shfl_xor(s, mk, 64);
        coef[j] = pexp * __builtin_amdgcn_rcpf(s);
      }

#pragma unroll
      for (int j = 0; j < 2; ++j) {
        __half2 cp = __float2half2_rn(coef[j]);
#pragma unroll
        for (int q = 0; q < 4; ++q) accp[j][q] = __hfma2(cp, uhp[j][q], accp[j][q]);
      }
    }
    __builtin_amdgcn_s_setprio(0);

    cur = (cur + 1 == 3) ? 0 : cur + 1;
  }

  // atomic accumulate into Sout replica
#pragma unroll
  for (int j = 0; j < 2; ++j) {
    float* dst = Sout + (size_t)(ic & 3)*SCE
               + (size_t)(b0 + bq*2 + j)*(C_*E_) + c*E_ + eh*8;
#pragma unroll
    for (int q = 0; q < 4; ++q) {
      float2 f = __half22float2(accp[j][q]);
      unsafeAtomicAdd(dst + q*2 + 0, f.x);
      unsafeAtomicAdd(dst + q*2 + 1, f.y);
    }
  }
}

// finalize: sum S2 replicas, squash over e (16-lane groups), write out.
__global__ __launch_bounds__(256)
void finalize(const float* __restrict__ S2, float* __restrict__ out)
{
  const int idx = blockIdx.x*256 + threadIdx.x;   // 0..32767
  float s = 0.f;
#pragma unroll
  for (int r = 0; r < NREP; ++r) s += S2[(size_t)r*SCE + idx];
  float sq = s * s;
  sq += __shfl_xor(sq, 1); sq += __shfl_xor(sq, 2);
  sq += __shfl_xor(sq, 4); sq += __shfl_xor(sq, 8);
  float scale = sq / (1.f + sq) / (sqrtf(sq) + 1e-8f);
  out[idx] = s * scale;
}

extern "C" void kernel_launch(void* const* d_in, const int* in_sizes, int n_in,
                              void* d_out, int out_size, void* d_ws, size_t ws_size,
                              hipStream_t stream)
{
  const float* x = (const float*)d_in[0];
  const float* W = (const float*)d_in[1];
  float* out     = (float*)d_out;

  char* ws = (char*)d_ws;
  float*   S0 = (float*)ws;                          ws += (size_t)NREP*SCE*4;    // 512 KB
  float*   S1 = (float*)ws;                          ws += (size_t)NREP*SCE*4;    // 512 KB
  float*   S2 = (float*)ws;                          ws += (size_t)NREP*SCE*4;    // 512 KB
  __half*  Wh = (__half*)ws;                         ws += (size_t)I_*C_*D_*E_*2; // 9.4 MB
  __half2* xh = (__half2*)ws;                                                    // 2.36 MB

  // atomic accumulators must start at zero each call
  hipMemsetAsync(S0, 0, (size_t)3*NREP*SCE*4, stream);

  dim3 pg(NIC * (B_/BC_));                           // 768 blocks (3/CU exact)

  // iter 0 (f32, uniform coef) + converts -> atomic S0
  caps_pass0<<<pg, 256, 0, stream>>>(x, W, S0, Wh, xh);
  // iter 1: v0 = squash(S0) inline -> atomic S1
  caps_pass_f16<false><<<pg, 256, 0, stream>>>(xh, (const char*)Wh, S0, nullptr, S1);
  // iter 2: v0+v1 = squash(S0)+squash(S1) inline -> atomic S2
  caps_pass_f16<true ><<<pg, 256, 0, stream>>>(xh, (const char*)Wh, S0, S1, S2);
  // squash(S2) -> out
  finalize<<<SCE/256, 256, 0, stream>>>(S2, out);
}

// Round 18
// 66.000 us; speedup vs baseline: 4.4311x; 4.4311x over previous
//
#include <hip/hip_runtime.h>
#include <hip/hip_fp16.h>

#define B_ 64
#define I_ 1152
#define C_ 32
#define E_ 16
#define D_ 8
#define BC_ 8                // batch rows per block (4 waves, j=2 each)
#define ICt 12               // i's per block
#define NIC (I_/ICt)         // 96 i-chunks
#define ICX (NIC/8)          // 12 i-chunks per XCD slab
#define WROW4 (C_*D_*E_/4)   // 1024 float4 per W[i] (f32)
#define SCE (B_*C_*E_)       // 32768 s-elements
#define SCE2 (SCE/2)         // 16384 half2 pairs
#define WIB 8192             // bytes per W[i] in f16 (32c x 16 granules x 16B)

// async global->LDS DMA, 16B per lane (dest = wave-uniform base + lane*16)
__device__ __forceinline__ void gload_lds16(const void* g, void* l) {
  typedef __attribute__((address_space(1))) const void GV;
  typedef __attribute__((address_space(3))) void LV;
  __builtin_amdgcn_global_load_lds((GV*)g, (LV*)l, 16, 0, 0);
}

#define WAITVM8() do { asm volatile("s_waitcnt vmcnt(8)" ::: "memory"); \
                       __builtin_amdgcn_sched_barrier(0); } while (0)
#define WAITVM4() do { asm volatile("s_waitcnt vmcnt(4)" ::: "memory"); \
                       __builtin_amdgcn_sched_barrier(0); } while (0)
#define WAITVM0() do { asm volatile("s_waitcnt vmcnt(0)" ::: "memory"); \
                       __builtin_amdgcn_sched_barrier(0); } while (0)
#define WAITLG0() do { asm volatile("s_waitcnt lgkmcnt(0)" ::: "memory"); \
                       __builtin_amdgcn_sched_barrier(0); } while (0)

typedef _Float16 h2v __attribute__((ext_vector_type(2)));

__device__ __forceinline__ float dot2f(__half2 a, __half2 b, float c) {
#if defined(__has_builtin)
#if __has_builtin(__builtin_amdgcn_fdot2)
  return __builtin_amdgcn_fdot2(__builtin_bit_cast(h2v, a),
                                __builtin_bit_cast(h2v, b), c, false);
#else
  float2 fa = __half22float2(a), fb = __half22float2(b);
  return fmaf(fa.x, fb.x, fmaf(fa.y, fb.y, c));
#endif
#else
  float2 fa = __half22float2(a), fb = __half22float2(b);
  return fmaf(fa.x, fb.x, fmaf(fa.y, fb.y, c));
#endif
}

__device__ __forceinline__ float h2bits(float a, float b) {
  return __builtin_bit_cast(float, __float22half2_rn({a, b}));
}

// ---------------- Pass 0 (f32 compute, uniform coef) + fused convert -------
// r9-proven structure: f32 W via global_load_lds, 3-buf 2-deep counted-vmcnt
// pipeline (4 loads/i, ladder 8/4/0), quad-rotate swizzle on global source.
// coef = 1/32 (softmax of zero logits). Epilogue (after partial store):
// distributed conversion for passes 1-2 -- this block converts W[i] -> f16
// granules for its chunk's i's where (ii&7)==bslab (each i converted exactly
// once grid-wide; source re-read from L2-hot global), and its own x slab
// (8 b x 12 i) -> duplicated half2 xh from the staged LDS copy.
__global__ __launch_bounds__(256)
void caps_pass0(const float* __restrict__ x, const float* __restrict__ W,
                __half* __restrict__ partial, __half* __restrict__ Wh,
                __half2* __restrict__ xh)
{
  __shared__ float4 Wl[3][1024];      // 3 x 16KB f32 W buffers
  __shared__ float4 xl[BC_*ICt*2];    // 192 float4 (3KB) f32 x

  const int t     = threadIdx.x;
  const int c     = t & 31;
  const int eh    = (t >> 5) & 1;
  const int bq    = t >> 6;
  const int xcd   = blockIdx.x & 7;
  const int sl    = blockIdx.x >> 3;  // 0..95
  const int ic    = xcd * ICX + (sl >> 3);
  const int bslab = sl & 7;
  const int b0    = bslab * BC_;
  const int i0    = ic * ICt;

  int fsrc[4];
#pragma unroll
  for (int k = 0; k < 4; ++k) {
    int cc = (t >> 5) + 8*k;
    fsrc[k] = cc*32 + ((c - cc) & 31);
  }

  if (t < BC_*ICt*2) {
    int b = t / (ICt*2), r = t % (ICt*2);
    xl[t] = ((const float4*)x)[ ((size_t)(b0 + b)*I_ + i0)*2 + r ];
  }

  const float4* wg = (const float4*)(W + (size_t)i0 * (C_*D_*E_));
#pragma unroll
  for (int k = 0; k < 4; ++k) gload_lds16(wg + fsrc[k],          &Wl[0][t + 256*k]);
#pragma unroll
  for (int k = 0; k < 4; ++k) gload_lds16(wg + WROW4 + fsrc[k],  &Wl[1][t + 256*k]);

  float acc[2][8];
#pragma unroll
  for (int j = 0; j < 2; ++j)
#pragma unroll
    for (int e = 0; e < 8; ++e) acc[j][e] = 0.f;

  int cur = 0;
  for (int ii = 0; ii < ICt; ++ii) {
    WAITLG0();
    __builtin_amdgcn_s_barrier();
    __builtin_amdgcn_sched_barrier(0);

    if (ii + 2 < ICt) {
      int pre = cur + 2; if (pre >= 3) pre -= 3;
      const float4* wn = wg + (size_t)(ii + 2) * WROW4;
#pragma unroll
      for (int k = 0; k < 4; ++k)
        gload_lds16(wn + fsrc[k], &Wl[pre][t + 256*k]);
    }

    if (ii < ICt - 2)       WAITVM8();
    else if (ii == ICt - 2) WAITVM4();
    else                    WAITVM0();
    __builtin_amdgcn_s_barrier();
    __builtin_amdgcn_sched_barrier(0);

    __builtin_amdgcn_s_setprio(1);
    float xv[2][8];
#pragma unroll
    for (int j = 0; j < 2; ++j) {
      float4 a = xl[(bq*2 + j)*(ICt*2) + ii*2 + 0];
      float4 b = xl[(bq*2 + j)*(ICt*2) + ii*2 + 1];
      xv[j][0]=a.x; xv[j][1]=a.y; xv[j][2]=a.z; xv[j][3]=a.w;
      xv[j][4]=b.x; xv[j][5]=b.y; xv[j][6]=b.z; xv[j][7]=b.w;
    }

    float uh[2][8];
#pragma unroll
    for (int j = 0; j < 2; ++j)
#pragma unroll
      for (int e = 0; e < 8; ++e) uh[j][e] = 0.f;

#pragma unroll
    for (int d = 0; d < D_; ++d) {
#pragma unroll
      for (int qq = 0; qq < 2; ++qq) {
        float4 wv = Wl[cur][c*32 + (((d*4 + eh*2 + qq) + c) & 31)];
        const int eb = qq*4;
#pragma unroll
        for (int j = 0; j < 2; ++j) {
          uh[j][eb+0] = fmaf(xv[j][d], wv.x, uh[j][eb+0]);
          uh[j][eb+1] = fmaf(xv[j][d], wv.y, uh[j][eb+1]);
          uh[j][eb+2] = fmaf(xv[j][d], wv.z, uh[j][eb+2]);
          uh[j][eb+3] = fmaf(xv[j][d], wv.w, uh[j][eb+3]);
        }
      }
    }

#pragma unroll
    for (int j = 0; j < 2; ++j)
#pragma unroll
      for (int e = 0; e < 8; ++e) acc[j][e] = fmaf((1.0f/C_), uh[j][e], acc[j][e]);
    __builtin_amdgcn_s_setprio(0);

    cur = (cur + 1 == 3) ? 0 : cur + 1;
  }

  // partial s (f16): [NIC][B][C][E], 16B store per j  (reduce0 critical path)
#pragma unroll
  for (int j = 0; j < 2; ++j) {
    size_t base = ((size_t)ic * B_ + (b0 + bq*2 + j)) * (C_*E_) + (size_t)c*E_ + eh*8;
    float4 o;
    o.x = h2bits(acc[j][0], acc[j][1]);
    o.y = h2bits(acc[j][2], acc[j][3]);
    o.z = h2bits(acc[j][4], acc[j][5]);
    o.w = h2bits(acc[j][6], acc[j][7]);
    *(float4*)(partial + base) = o;
  }

  // ---- epilogue converts (off reduce0's critical path) ----
  for (int ii = bslab; ii < ICt; ii += 8) {
    const int i = i0 + ii;
    const float4* src = (const float4*)(W + (size_t)i * (C_*D_*E_));
#pragma unroll
    for (int g = 0; g < 2; ++g) {
      int G  = t*2 + g;                 // granule 0..511
      int cc = G >> 4, q = G & 15;
      int d  = q >> 1, eo = q & 1;
      const float4* s4 = src + (cc*8 + d)*4 + eo*2;
      float4 a = s4[0], b = s4[1];
      float4 o;
      o.x = h2bits(a.x, a.y); o.y = h2bits(a.z, a.w);
      o.z = h2bits(b.x, b.y); o.w = h2bits(b.z, b.w);
      *(float4*)(Wh + (size_t)i * 4096 + G*8) = o;
    }
  }
  if (t < BC_*ICt*2) {
    int b = t / (ICt*2), r = t % (ICt*2);
    float4 a = xl[t];
    float4 o;
    o.x = h2bits(a.x, a.x); o.y = h2bits(a.y, a.y);
    o.z = h2bits(a.z, a.z); o.w = h2bits(a.w, a.w);
    size_t idx = ((size_t)(b0 + b)*I_ + (i0 + (r >> 1)))*D_ + (r & 1)*4;
    *(float4*)(xh + idx) = o;
  }
}

// ---------------- Passes 1,2: packed-f16 (r12 structure + setprio) ---------
template<int MODE>
__global__ __launch_bounds__(256)
void caps_pass_f16(const __half2* __restrict__ xh, const char* __restrict__ Wh,
                   const float* __restrict__ vacc, __half* __restrict__ partial)
{
  __shared__ float4 Wl[3][1024];      // 3 x 16KB buffers (2 W-i's each)
  __shared__ __half2 xl[BC_*ICt*D_];  // 768 half2 (3KB)

  const int t   = threadIdx.x;
  const int c   = t & 31;
  const int eh  = (t >> 5) & 1;
  const int bq  = t >> 6;
  const int xcd = blockIdx.x & 7;
  const int sl  = blockIdx.x >> 3;    // 0..95
  const int ic  = xcd * ICX + (sl >> 3);
  const int b0  = (sl & 7) * BC_;
  const int i0  = ic * ICt;

  int fsrc[2];
#pragma unroll
  for (int k = 0; k < 2; ++k) {
    int g = t + 256*k, cc = g >> 4, q = g & 15;
    fsrc[k] = cc*256 + ((q ^ (cc & 15)) << 4);    // byte offset in Wh[i]
  }

  __half2 vrp[2][4];
#pragma unroll
  for (int j = 0; j < 2; ++j) {
    const float4* vp = (const float4*)(vacc + (((size_t)(b0 + bq*2 + j)*C_ + c)*E_ + eh*8));
    float4 a = vp[0], b = vp[1];
    vrp[j][0] = __float22half2_rn({a.x, a.y});
    vrp[j][1] = __float22half2_rn({a.z, a.w});
    vrp[j][2] = __float22half2_rn({b.x, b.y});
    vrp[j][3] = __float22half2_rn({b.z, b.w});
  }

  if (t < BC_*ICt*D_/4) {
    int b = t / 24, r = t % 24;
    float4 v = ((const float4*)(xh + ((size_t)(b0 + b)*I_ + i0)*D_))[r];
    ((float4*)xl)[b*24 + r] = v;
  }

  const char* wg = Wh + (size_t)i0 * WIB;
#pragma unroll
  for (int k = 0; k < 4; ++k)
    gload_lds16(wg + (k>>1)*WIB + fsrc[k&1], (char*)&Wl[0][0] + (t + 256*k)*16);
#pragma unroll
  for (int k = 0; k < 4; ++k)
    gload_lds16(wg + WIB*2 + (k>>1)*WIB + fsrc[k&1], (char*)&Wl[1][0] + (t + 256*k)*16);

  __half2 accp[2][4];
#pragma unroll
  for (int j = 0; j < 2; ++j)
#pragma unroll
    for (int q = 0; q < 4; ++q) accp[j][q] = __half2{__half(0.f), __half(0.f)};

  int cur = 0;
  for (int p = 0; p < ICt/2; ++p) {
    WAITLG0();
    __builtin_amdgcn_s_barrier();
    __builtin_amdgcn_sched_barrier(0);

    if (p + 2 < ICt/2) {
      int pre = cur + 2; if (pre >= 3) pre -= 3;
      const char* wn = wg + (size_t)(p + 2) * (2*WIB);
#pragma unroll
      for (int k = 0; k < 4; ++k)
        gload_lds16(wn + (k>>1)*WIB + fsrc[k&1], (char*)&Wl[pre][0] + (t + 256*k)*16);
    }

    if (p < ICt/2 - 2)       WAITVM8();
    else if (p == ICt/2 - 2) WAITVM4();
    else                     WAITVM0();
    __builtin_amdgcn_s_barrier();
    __builtin_amdgcn_sched_barrier(0);

    __builtin_amdgcn_s_setprio(1);
#pragma unroll
    for (int il = 0; il < 2; ++il) {
      const int ii = p*2 + il;

      __half2 xd0[8], xd1[8];
      {
        const float4* xr = (const float4*)xl;
        float4 a0 = xr[((bq*2 + 0)*ICt + ii)*2 + 0];
        float4 b0v = xr[((bq*2 + 0)*ICt + ii)*2 + 1];
        float4 a1 = xr[((bq*2 + 1)*ICt + ii)*2 + 0];
        float4 b1v = xr[((bq*2 + 1)*ICt + ii)*2 + 1];
        xd0[0]=__builtin_bit_cast(__half2,a0.x); xd0[1]=__builtin_bit_cast(__half2,a0.y);
        xd0[2]=__builtin_bit_cast(__half2,a0.z); xd0[3]=__builtin_bit_cast(__half2,a0.w);
        xd0[4]=__builtin_bit_cast(__half2,b0v.x); xd0[5]=__builtin_bit_cast(__half2,b0v.y);
        xd0[6]=__builtin_bit_cast(__half2,b0v.z); xd0[7]=__builtin_bit_cast(__half2,b0v.w);
        xd1[0]=__builtin_bit_cast(__half2,a1.x); xd1[1]=__builtin_bit_cast(__half2,a1.y);
        xd1[2]=__builtin_bit_cast(__half2,a1.z); xd1[3]=__builtin_bit_cast(__half2,a1.w);
        xd1[4]=__builtin_bit_cast(__half2,b1v.x); xd1[5]=__builtin_bit_cast(__half2,b1v.y);
        xd1[6]=__builtin_bit_cast(__half2,b1v.z); xd1[7]=__builtin_bit_cast(__half2,b1v.w);
      }

      __half2 uhp[2][4];
#pragma unroll
      for (int j = 0; j < 2; ++j)
#pragma unroll
        for (int q = 0; q < 4; ++q) uhp[j][q] = __half2{__half(0.f), __half(0.f)};

      const char* wrow = (const char*)&Wl[cur][0] + il*WIB + c*256;
#pragma unroll
      for (int d = 0; d < D_; ++d) {
        float4 w4 = *(const float4*)(wrow + ((((d*2 + eh) ^ (c & 15))) << 4));
        __half2 w0 = __builtin_bit_cast(__half2, w4.x);
        __half2 w1 = __builtin_bit_cast(__half2, w4.y);
        __half2 w2 = __builtin_bit_cast(__half2, w4.z);
        __half2 w3 = __builtin_bit_cast(__half2, w4.w);
        uhp[0][0] = __hfma2(xd0[d], w0, uhp[0][0]);
        uhp[0][1] = __hfma2(xd0[d], w1, uhp[0][1]);
        uhp[0][2] = __hfma2(xd0[d], w2, uhp[0][2]);
        uhp[0][3] = __hfma2(xd0[d], w3, uhp[0][3]);
        uhp[1][0] = __hfma2(xd1[d], w0, uhp[1][0]);
        uhp[1][1] = __hfma2(xd1[d], w1, uhp[1][1]);
        uhp[1][2] = __hfma2(xd1[d], w2, uhp[1][2]);
        uhp[1][3] = __hfma2(xd1[d], w3, uhp[1][3]);
      }

      float coef[2];
#pragma unroll
      for (int j = 0; j < 2; ++j) {
        float lg = 0.f;
#pragma unroll
        for (int q = 0; q < 4; ++q) lg = dot2f(uhp[j][q], vrp[j][q], lg);
        lg += __shfl_xor(lg, 32, 64);          // combine e-halves
        float pexp = __expf(lg);               // no max-sub: |lg| bounded
        float s = pexp;
#pragma unroll
        for (int mk = 16; mk >= 1; mk >>= 1) s += __shfl_xor(s, mk, 64);
        coef[j] = pexp * __builtin_amdgcn_rcpf(s);
      }

#pragma unroll
      for (int j = 0; j < 2; ++j) {
        __half2 cp = __float2half2_rn(coef[j]);
#pragma unroll
        for (int q = 0; q < 4; ++q) accp[j][q] = __hfma2(cp, uhp[j][q], accp[j][q]);
      }
    }
    __builtin_amdgcn_s_setprio(0);

    cur = (cur + 1 == 3) ? 0 : cur + 1;
  }

#pragma unroll
  for (int j = 0; j < 2; ++j) {
    size_t base = ((size_t)ic * B_ + (b0 + bq*2 + j)) * (C_*E_) + (size_t)c*E_ + eh*8;
    float4 o;
    o.x = __builtin_bit_cast(float, accp[j][0]);
    o.y = __builtin_bit_cast(float, accp[j][1]);
    o.z = __builtin_bit_cast(float, accp[j][2]);
    o.w = __builtin_bit_cast(float, accp[j][3]);
    *(float4*)(partial + base) = o;
  }
}

// Fused reduce+squash on f16 partial: 512 blocks x 256 thr (2 blocks/CU).
// thread (pair = bid*32 + (t&31), part = t>>5) sums 12 chunks; LDS combine of
// 8 parts; squash over e. mode 0: vacc = v ; 1: vacc += v ; 2: out = v
__global__ __launch_bounds__(256)
void reduce_squash(const __half2* __restrict__ partial, float* __restrict__ vacc,
                   float* __restrict__ out, int mode)
{
  __shared__ float2 sm[256];
  const int t    = threadIdx.x;
  const int pair = blockIdx.x*32 + (t & 31);
  const int part = t >> 5;
  const __half2* p = partial + (size_t)(part*(NIC/8)) * SCE2 + pair;
  float2 s = {0.f, 0.f};
#pragma unroll
  for (int k = 0; k < NIC/8; ++k) {
    float2 f = __half22float2(p[(size_t)k * SCE2]);
    s.x += f.x; s.y += f.y;
  }
  sm[t] = s;
  __syncthreads();
  if (t < 32) {
    float2 tot = {0.f, 0.f};
#pragma unroll
    for (int pp = 0; pp < 8; ++pp) {
      float2 v = sm[t + 32*pp];
      tot.x += v.x; tot.y += v.y;
    }
    float sq = tot.x*tot.x + tot.y*tot.y;
    sq += __shfl_xor(sq, 1); sq += __shfl_xor(sq, 2); sq += __shfl_xor(sq, 4);
    float scale = sq / (1.f + sq) / (sqrtf(sq) + 1e-8f);
    float vx = scale * tot.x, vy = scale * tot.y;
    const int cell = pair * 2;
    if (mode == 0)      { vacc[cell] = vx;  vacc[cell+1] = vy;  }
    else if (mode == 1) { vacc[cell] += vx; vacc[cell+1] += vy; }
    else                { out[cell]  = vx;  out[cell+1]  = vy;  }
  }
}

extern "C" void kernel_launch(void* const* d_in, const int* in_sizes, int n_in,
                              void* d_out, int out_size, void* d_ws, size_t ws_size,
                              hipStream_t stream)
{
  const float* x = (const float*)d_in[0];
  const float* W = (const float*)d_in[1];
  float* out     = (float*)d_out;

  char* ws = (char*)d_ws;
  __half*  partial = (__half*)ws;                    ws += (size_t)NIC*SCE*2;     // 6.3 MB
  float*   vacc    = (float*)ws;                     ws += (size_t)SCE*4;         // 128 KB
  __half*  Wh      = (__half*)ws;                    ws += (size_t)I_*C_*D_*E_*2; // 9.4 MB
  __half2* xh      = (__half2*)ws;                                               // 2.36 MB

  dim3 pg(NIC * (B_/BC_));                           // 768 blocks (3/CU exact)
  const int rg = SCE2 / 32;                          // 512 blocks

  // iter 0 (f32) + fused W/x -> f16 conversion
  caps_pass0<<<pg, 256, 0, stream>>>(x, W, partial, Wh, xh);
  reduce_squash<<<rg, 256, 0, stream>>>((const __half2*)partial, vacc, nullptr, 0);
  // iter 1: logits = u_hat . v0
  caps_pass_f16<0><<<pg, 256, 0, stream>>>(xh, (const char*)Wh, vacc, partial);
  reduce_squash<<<rg, 256, 0, stream>>>((const __half2*)partial, vacc, nullptr, 1);
  // iter 2: logits = u_hat . (v0+v1)
  caps_pass_f16<1><<<pg, 256, 0, stream>>>(xh, (const char*)Wh, vacc, partial);
  reduce_squash<<<rg, 256, 0, stream>>>((const __half2*)partial, vacc, out, 2);
}